// Round 4
// baseline (159.807 us; speedup 1.0000x reference)
//
#include <hip/hip_runtime.h>
#include <hip/hip_bf16.h>

// Two pairwise MLPs (ChG, DG) over 1024x1024 pairs, then A_chg @ A_gd, sigmoid.
// Outputs concat: [0:1M) sigmoid(A_chd), [1M:2M) A_chg, [2M:3M) A_gd (fp32).
//
// R17 = R16 with gemm_sig retiled BK 64 -> 256 (4 K-iterations, 8 barriers vs
// 32). Decomposition from R16 counters: dur_us contains one 42us harness fill
// + prep ~5 + branch ~43 + gemm ~40. gemm at 40us = 2.5% MFMA util was pure
// barrier-drain (2 MFMAs between syncthreads). New loop: 8 MFMAs + 16
// ds_read_b128 per iter, register prefetch (8 uint4/thread) issued right
// after the first barrier so load latency hides under the MFMA phase.
// Even/odd k-slice dual-accumulator grouping preserved -> accumulation order
// bitwise identical to R16. prep / branch_kernel byte-identical to R16.

typedef _Float16 half8 __attribute__((ext_vector_type(8)));
typedef float floatx4 __attribute__((ext_vector_type(4)));
typedef float floatx2 __attribute__((ext_vector_type(2)));

union U4H8 { uint4 u; half8 h; };
union PKH8 { uint4 u; _Float16 h[8]; };
union PKH4 { uint2 u; _Float16 h[4]; };

// ---------------------------------------------------------------- prep
// blocks 0..2047: hlhr (fp16): seg0 HL_chg(+b0c), seg1 HR_chg,
//                 seg2 HL_dg(+b0d), seg3 HR_dg; each [1024][128]
// blocks 2048..2111: w1frag[br][f=mt*4+ks][lane][j] =
//                 f16( W1[ks*32+(lane>>4)*8+j][mt*16+(lane&15)] )  (A-layout of W1^T)
__global__ __launch_bounds__(256) void prep(
    const float* __restrict__ Xch, const float* __restrict__ Xg,
    const float* __restrict__ Xd,
    const float* __restrict__ Wc0, const float* __restrict__ bc0,
    const float* __restrict__ Wd0, const float* __restrict__ bd0,
    const float* __restrict__ W1c, const float* __restrict__ W1d,
    _Float16* __restrict__ hlhr, _Float16* __restrict__ w1frag)
{
    int bid = blockIdx.x;
    if (bid < 2048) {
        int t = bid * 256 + threadIdx.x;   // 524288 threads
        int seg = t >> 17;
        int i = (t >> 7) & 1023;
        int k = t & 127;
        const float* X;
        const float* W;
        float s = 0.f;
        int wo = 0;
        if (seg == 0)      { X = Xch; W = Wc0; s = bc0[k]; }
        else if (seg == 1) { X = Xg;  W = Wc0; wo = 5; }
        else if (seg == 2) { X = Xg;  W = Wd0; s = bd0[k]; }
        else               { X = Xd;  W = Wd0; wo = 5; }
#pragma unroll
        for (int j = 0; j < 5; ++j)
            s += X[i * 5 + j] * W[(wo + j) * 128 + k];
        hlhr[t] = (_Float16)s;   // fp32 dot, one RNE round to fp16
    } else {
        int t = (bid - 2048) * 256 + threadIdx.x;   // 16384 threads
        int br   = t >> 13;
        int f    = (t >> 9) & 15;
        int lane = (t >> 3) & 63;
        int j    = t & 7;
        int mt = f >> 2, ks = f & 3;
        int row = ks * 32 + (lane >> 4) * 8 + j;    // k of W1
        int col = mt * 16 + (lane & 15);            // n of W1
        const float* W = br ? W1d : W1c;
        w1frag[t] = (_Float16)W[row * 64 + col];
    }
}

// ---------------------------------------------------------------- branch
#define LC 16          // l-values per block
#define PSTRIDE 69     // part[] pair stride in floats: 4 quads * 17 + 1

__global__ __launch_bounds__(256, 2) void branch_kernel(
    const _Float16* __restrict__ hlhr,
    const float* __restrict__ b1_chg, const float* __restrict__ wr_chg, const float* __restrict__ br_chg,
    const float* __restrict__ b1_dg,  const float* __restrict__ wr_dg,  const float* __restrict__ br_dg,
    const _Float16* __restrict__ w1frag,
    float* __restrict__ d_out,
    _Float16* __restrict__ wsh)   // [0:1M) Achg f16 [ch][g], [1M:2M) AgdT f16 [d][g]
{
    __shared__ _Float16 hl_tile[LC * 128];        // 4 KB
    __shared__ float part[64 * PSTRIDE];          // per-quad y partials [p][q*17+li] (17.7 KB)

    const int bz = blockIdx.z;
    const _Float16* HL = hlhr + (bz ? 262144 : 0);
    const _Float16* HR = hlhr + (bz ? 393216 : 131072);
    const float* b1 = bz ? b1_dg : b1_chg;
    const float* wr = bz ? wr_dg : wr_chg;
    const float brv = bz ? br_dg[0] : br_chg[0];
    float* outA = d_out + (bz ? 2097152 : 1048576);
    _Float16* outB = wsh + (bz ? 1048576 : 0);

    const int tid = threadIdx.x;
    const int lane = tid & 63, wave = tid >> 6;
    const int m = lane & 15, quad = lane >> 4;
    const int lbase = blockIdx.y * LC;
    const int rbase = blockIdx.x * 64;
    const int rm = rbase + wave * 16 + m;   // this lane's pair (column)
    const int p = wave * 16 + m;            // pair index within block

    {   // stage hl tile (fp16): LC*128 halves = 256 uint4
        const uint4* src = (const uint4*)(HL + lbase * 128);
        uint4* dst = (uint4*)hl_tile;
        dst[tid] = src[tid];
    }

    // hr in B-frag k-order (fp16): k = ks*32 + quad*8 + j
    half8 hr16[4];
#pragma unroll
    for (int ks = 0; ks < 4; ++ks)
        hr16[ks] = *(const half8*)(HR + rm * 128 + ks * 32 + quad * 8);

    // W1^T A-fragments (constant across the loop)
    half8 w1f[4][4];   // [mt][ks]
    {
        const uint4* wf = (const uint4*)(w1frag + bz * 8192);
#pragma unroll
        for (int f = 0; f < 16; ++f) {
            U4H8 t; t.u = wf[f * 64 + lane];
            w1f[f >> 2][f & 3] = t.h;
        }
    }

    // per-lane n-slice constants: n = mt*16 + quad*4 + r
    floatx4 b1q[4], wr4[4];
#pragma unroll
    for (int mt = 0; mt < 4; ++mt) {
        b1q[mt] = *(const floatx4*)(b1 + mt * 16 + quad * 4);
        wr4[mt] = *(const floatx4*)(wr + mt * 16 + quad * 4);
    }

    const floatx4 z4 = (floatx4){0.f, 0.f, 0.f, 0.f};
    half8 hz;
#pragma unroll
    for (int j = 0; j < 8; ++j) hz[j] = (_Float16)0.f;

    __syncthreads();

#pragma unroll 2
    for (int li = 0; li < LC; ++li) {
        const _Float16* hlp = hl_tile + li * 128;

        // h = relu(hl16 + hr16) in packed fp16 -> B-fragments
        half8 bfr[4];
#pragma unroll
        for (int ks = 0; ks < 4; ++ks) {
            half8 hl8 = *(const half8*)(hlp + ks * 32 + quad * 8);
            bfr[ks] = __builtin_elementwise_max(hl8 + hr16[ks], hz);
        }

        // b1 folded into the FIRST MFMA's C operand (no acc-init copies;
        // same per-element accumulation order as acc=b1q + ks=0..3 chain).
        floatx4 acc[4];
#pragma unroll
        for (int mt = 0; mt < 4; ++mt)
            acc[mt] = __builtin_amdgcn_mfma_f32_16x16x32_f16(w1f[mt][0], bfr[0], b1q[mt], 0, 0, 0);
#pragma unroll
        for (int ks = 1; ks < 4; ++ks)
#pragma unroll
            for (int mt = 0; mt < 4; ++mt)
                acc[mt] = __builtin_amdgcn_mfma_f32_16x16x32_f16(w1f[mt][ks], bfr[ks], acc[mt], 0, 0, 0);

        // acc[mt][r] = h1[pair rm][n = mt*16+quad*4+r] + b1;  dot with Wr.
        // floatx4 accumulate (pk_f32-friendly, no lane-extract movs).
        floatx4 y4 = z4;
#pragma unroll
        for (int mt = 0; mt < 4; ++mt)
            y4 += __builtin_elementwise_max(acc[mt], z4) * wr4[mt];
        float y = (y4[0] + y4[1]) + (y4[2] + y4[3]);

        // quad partial; cross-quad reduction deferred to epilogue.
        part[p * PSTRIDE + quad * 17 + li] = y;
    }

    __syncthreads();

    // ---- epilogue pass 1: [li][pp] order -> outA (both) + outB (bz==0)
    {
        int li = tid >> 4;            // 0..15
        int p0 = (tid & 15) * 4;      // 0,4,..,60
        float v[4];
#pragma unroll
        for (int j = 0; j < 4; ++j) {
            const float* q = part + (p0 + j) * PSTRIDE + li;
            float yv = ((q[0] + q[17]) + (q[34] + q[51])) + brv;
            v[j] = yv > 0.f ? yv : (__expf(yv) - 1.f);   // elu
        }
        *(float4*)(outA + (lbase + li) * 1024 + rbase + p0) =
            make_float4(v[0], v[1], v[2], v[3]);
        if (bz == 0) {
            PKH4 pk;
#pragma unroll
            for (int j = 0; j < 4; ++j) pk.h[j] = (_Float16)v[j];
            *(uint2*)(outB + (lbase + li) * 1024 + rbase + p0) = pk.u;
        }
    }
    // ---- epilogue pass 2 (bz==1): [pp][li] order -> AgdT transposed
    if (bz == 1) {
        int pp = tid >> 2;            // 0..63
        int li0 = (tid & 3) * 4;      // 0,4,8,12
        PKH4 pk;
#pragma unroll
        for (int j = 0; j < 4; ++j) {
            const float* q = part + pp * PSTRIDE + li0 + j;
            float yv = ((q[0] + q[17]) + (q[34] + q[51])) + brv;
            float v = yv > 0.f ? yv : (__expf(yv) - 1.f);
            pk.h[j] = (_Float16)v;
        }
        *(uint2*)(outB + (rbase + pp) * 1024 + lbase + li0) = pk.u;
    }
}

// ---------------------------------------------------------------- final GEMM + sigmoid
// C[ch][d] = sum_g Achg[ch][g]*Agd[g][d]; fp16 MFMA, fp32 accum.
// R17: 32x32 tiles, BK=256 -> 4 K-iterations (was 16). Register prefetch
// (8 uint4/thread) issued right after the post-write barrier; 8 MFMAs +
// 16 ds_read_b128 per iteration. Dual accumulator keeps the even/odd
// k-slice grouping -> accumulation order bitwise identical to BK=64 version.
#define GSTR 264   // LDS row stride in halves (+8 pad; bank-balanced)

__global__ __launch_bounds__(256, 4) void gemm_sig(
    const _Float16* __restrict__ Ahf,   // [1024][1024] ch x g
    const _Float16* __restrict__ BThf,  // [1024][1024] d x g
    float* __restrict__ out0)
{
    __shared__ _Float16 At[32 * GSTR];   // 16.5 KB
    __shared__ _Float16 Bt[32 * GSTR];   // 16.5 KB

    const int tid = threadIdx.x, lane = tid & 63, wave = tid >> 6;
    const int m = lane & 15, quad = lane >> 4;
    const int chbase = blockIdx.y * 32, dbase = blockIdx.x * 32;
    const int wrow = (wave >> 1) * 16, wcol = (wave & 1) * 16;

    floatx4 acc0 = (floatx4){0.f, 0.f, 0.f, 0.f};
    floatx4 acc1 = (floatx4){0.f, 0.f, 0.f, 0.f};

    // staging map: row = tid>>3 (0..31), 4 uint4 per array along K:
    // uint4 col index c = (tid&7) + i*8  (i=0..3); 8 threads cover a row's
    // 32 uint4 (256 halves). Coalesced: 8 lanes x 16B = 128B segments.
    const int row = tid >> 3, c8 = tid & 7;
    const _Float16* gA = Ahf + (chbase + row) * 1024 + c8 * 8;
    const _Float16* gB = BThf + (dbase + row) * 1024 + c8 * 8;

    uint4 ra[4], rb[4];
#pragma unroll
    for (int i = 0; i < 4; ++i) {
        ra[i] = *(const uint4*)(gA + i * 64);   // i*8 uint4 = i*64 halves
        rb[i] = *(const uint4*)(gB + i * 64);
    }

#pragma unroll
    for (int kb = 0; kb < 4; ++kb) {
        // write staged regs -> LDS
#pragma unroll
        for (int i = 0; i < 4; ++i) {
            *(uint4*)(At + row * GSTR + (c8 + i * 8) * 8) = ra[i];
            *(uint4*)(Bt + row * GSTR + (c8 + i * 8) * 8) = rb[i];
        }
        __syncthreads();

        // prefetch next K-block (latency hides under the MFMA phase)
        if (kb < 3) {
#pragma unroll
            for (int i = 0; i < 4; ++i) {
                ra[i] = *(const uint4*)(gA + (kb + 1) * 256 + i * 64);
                rb[i] = *(const uint4*)(gB + (kb + 1) * 256 + i * 64);
            }
        }

        // 8 k-slices of K=32; even -> acc0, odd -> acc1 (same global slice
        // parity and order as the BK=64 dual-acc loop -> bitwise identical).
#pragma unroll
        for (int ks = 0; ks < 8; ks += 2) {
            half8 a0 = *(const half8*)(At + (wrow + m) * GSTR + ks * 32 + quad * 8);
            half8 b0 = *(const half8*)(Bt + (wcol + m) * GSTR + ks * 32 + quad * 8);
            half8 a1 = *(const half8*)(At + (wrow + m) * GSTR + (ks + 1) * 32 + quad * 8);
            half8 b1 = *(const half8*)(Bt + (wcol + m) * GSTR + (ks + 1) * 32 + quad * 8);
            acc0 = __builtin_amdgcn_mfma_f32_16x16x32_f16(a0, b0, acc0, 0, 0, 0);
            acc1 = __builtin_amdgcn_mfma_f32_16x16x32_f16(a1, b1, acc1, 0, 0, 0);
        }
        __syncthreads();
    }

    floatx4 acc = acc0 + acc1;
#pragma unroll
    for (int r = 0; r < 4; ++r) {
        int row_o = chbase + wrow + quad * 4 + r;
        int col_o = dbase + wcol + m;
        // sigmoid via fast exp + hw rcp (~1e-7 abs drift, well under tolerance)
        float e = __expf(-acc[r]);
        out0[row_o * 1024 + col_o] = __builtin_amdgcn_rcpf(1.f + e);
    }
}

// ---------------------------------------------------------------- launch
extern "C" void kernel_launch(void* const* d_in, const int* in_sizes, int n_in,
                              void* d_out, int out_size, void* d_ws, size_t ws_size,
                              hipStream_t stream) {
    const float* Xch = (const float*)d_in[0];
    const float* Xg  = (const float*)d_in[1];
    const float* Xd  = (const float*)d_in[2];
    const float* Wc0 = (const float*)d_in[3];
    const float* bc0 = (const float*)d_in[4];
    const float* Wc1 = (const float*)d_in[5];
    const float* bc1 = (const float*)d_in[6];
    const float* Wcr = (const float*)d_in[7];
    const float* bcr = (const float*)d_in[8];
    const float* Wd0 = (const float*)d_in[9];
    const float* bd0 = (const float*)d_in[10];
    const float* Wd1 = (const float*)d_in[11];
    const float* bd1 = (const float*)d_in[12];
    const float* Wdr = (const float*)d_in[13];
    const float* bdr = (const float*)d_in[14];

    float* out = (float*)d_out;
    _Float16* hlhr = (_Float16*)d_ws;            // 4x1024x128 fp16 = 1 MB
    _Float16* wsh = hlhr + 524288;               // Achg f16 1M + AgdT f16 1M
    _Float16* w1frag = wsh + 2097152;            // 16384 f16

    prep<<<2112, 256, 0, stream>>>(Xch, Xg, Xd, Wc0, bc0, Wd0, bd0, Wc1, Wd1,
                                   hlhr, w1frag);

    dim3 gb(16, 64, 2);   // (r-chunks of 64, l-chunks of 16, branch)
    branch_kernel<<<gb, 256, 0, stream>>>(hlhr, bc1, Wcr, bcr, bd1, Wdr, bdr,
                                          w1frag, out, wsh);

    dim3 gg(32, 32);
    gemm_sig<<<gg, 256, 0, stream>>>(wsh, wsh + 1048576, out);
}

// Round 5
// 129.823 us; speedup vs baseline: 1.2310x; 1.2310x over previous
//
#include <hip/hip_runtime.h>
#include <hip/hip_bf16.h>

// Two pairwise MLPs (ChG, DG) over 1024x1024 pairs, then A_chg @ A_gd, sigmoid.
// Outputs concat: [0:1M) sigmoid(A_chd), [1M:2M) A_chg, [2M:3M) A_gd (fp32).
//
// R18 = R17 with the gemm_sig spill fixed. R17's BK=256 staged 8 uint4/thread
// across a barrier -> compiler spilled to scratch: WRITE_SIZE 88.8 MB vs 4.3 MB
// legit (85 MB scratch), 2.6 TB/s of pure overhead, VALUBusy 1.3%. R18 uses
// BK=128: 2 uint4/thread per matrix (16 VGPRs staged, vs R16's 8 / R17's 32),
// 8 K-iterations (16 barriers vs R16's 32), 8 ds_read_b128 + 4 MFMA per iter.
// Plain __launch_bounds__(256) (no min-waves) so the allocator never spills.
// Even/odd k-slice dual-accumulator, ascending order -> accumulation bitwise
// identical to R16/R9. prep / branch_kernel byte-identical to R17.

typedef _Float16 half8 __attribute__((ext_vector_type(8)));
typedef float floatx4 __attribute__((ext_vector_type(4)));
typedef float floatx2 __attribute__((ext_vector_type(2)));

union U4H8 { uint4 u; half8 h; };
union PKH8 { uint4 u; _Float16 h[8]; };
union PKH4 { uint2 u; _Float16 h[4]; };

// ---------------------------------------------------------------- prep
// blocks 0..2047: hlhr (fp16): seg0 HL_chg(+b0c), seg1 HR_chg,
//                 seg2 HL_dg(+b0d), seg3 HR_dg; each [1024][128]
// blocks 2048..2111: w1frag[br][f=mt*4+ks][lane][j] =
//                 f16( W1[ks*32+(lane>>4)*8+j][mt*16+(lane&15)] )  (A-layout of W1^T)
__global__ __launch_bounds__(256) void prep(
    const float* __restrict__ Xch, const float* __restrict__ Xg,
    const float* __restrict__ Xd,
    const float* __restrict__ Wc0, const float* __restrict__ bc0,
    const float* __restrict__ Wd0, const float* __restrict__ bd0,
    const float* __restrict__ W1c, const float* __restrict__ W1d,
    _Float16* __restrict__ hlhr, _Float16* __restrict__ w1frag)
{
    int bid = blockIdx.x;
    if (bid < 2048) {
        int t = bid * 256 + threadIdx.x;   // 524288 threads
        int seg = t >> 17;
        int i = (t >> 7) & 1023;
        int k = t & 127;
        const float* X;
        const float* W;
        float s = 0.f;
        int wo = 0;
        if (seg == 0)      { X = Xch; W = Wc0; s = bc0[k]; }
        else if (seg == 1) { X = Xg;  W = Wc0; wo = 5; }
        else if (seg == 2) { X = Xg;  W = Wd0; s = bd0[k]; }
        else               { X = Xd;  W = Wd0; wo = 5; }
#pragma unroll
        for (int j = 0; j < 5; ++j)
            s += X[i * 5 + j] * W[(wo + j) * 128 + k];
        hlhr[t] = (_Float16)s;   // fp32 dot, one RNE round to fp16
    } else {
        int t = (bid - 2048) * 256 + threadIdx.x;   // 16384 threads
        int br   = t >> 13;
        int f    = (t >> 9) & 15;
        int lane = (t >> 3) & 63;
        int j    = t & 7;
        int mt = f >> 2, ks = f & 3;
        int row = ks * 32 + (lane >> 4) * 8 + j;    // k of W1
        int col = mt * 16 + (lane & 15);            // n of W1
        const float* W = br ? W1d : W1c;
        w1frag[t] = (_Float16)W[row * 64 + col];
    }
}

// ---------------------------------------------------------------- branch
#define LC 16          // l-values per block
#define PSTRIDE 69     // part[] pair stride in floats: 4 quads * 17 + 1

__global__ __launch_bounds__(256, 2) void branch_kernel(
    const _Float16* __restrict__ hlhr,
    const float* __restrict__ b1_chg, const float* __restrict__ wr_chg, const float* __restrict__ br_chg,
    const float* __restrict__ b1_dg,  const float* __restrict__ wr_dg,  const float* __restrict__ br_dg,
    const _Float16* __restrict__ w1frag,
    float* __restrict__ d_out,
    _Float16* __restrict__ wsh)   // [0:1M) Achg f16 [ch][g], [1M:2M) AgdT f16 [d][g]
{
    __shared__ _Float16 hl_tile[LC * 128];        // 4 KB
    __shared__ float part[64 * PSTRIDE];          // per-quad y partials [p][q*17+li] (17.7 KB)

    const int bz = blockIdx.z;
    const _Float16* HL = hlhr + (bz ? 262144 : 0);
    const _Float16* HR = hlhr + (bz ? 393216 : 131072);
    const float* b1 = bz ? b1_dg : b1_chg;
    const float* wr = bz ? wr_dg : wr_chg;
    const float brv = bz ? br_dg[0] : br_chg[0];
    float* outA = d_out + (bz ? 2097152 : 1048576);
    _Float16* outB = wsh + (bz ? 1048576 : 0);

    const int tid = threadIdx.x;
    const int lane = tid & 63, wave = tid >> 6;
    const int m = lane & 15, quad = lane >> 4;
    const int lbase = blockIdx.y * LC;
    const int rbase = blockIdx.x * 64;
    const int rm = rbase + wave * 16 + m;   // this lane's pair (column)
    const int p = wave * 16 + m;            // pair index within block

    {   // stage hl tile (fp16): LC*128 halves = 256 uint4
        const uint4* src = (const uint4*)(HL + lbase * 128);
        uint4* dst = (uint4*)hl_tile;
        dst[tid] = src[tid];
    }

    // hr in B-frag k-order (fp16): k = ks*32 + quad*8 + j
    half8 hr16[4];
#pragma unroll
    for (int ks = 0; ks < 4; ++ks)
        hr16[ks] = *(const half8*)(HR + rm * 128 + ks * 32 + quad * 8);

    // W1^T A-fragments (constant across the loop)
    half8 w1f[4][4];   // [mt][ks]
    {
        const uint4* wf = (const uint4*)(w1frag + bz * 8192);
#pragma unroll
        for (int f = 0; f < 16; ++f) {
            U4H8 t; t.u = wf[f * 64 + lane];
            w1f[f >> 2][f & 3] = t.h;
        }
    }

    // per-lane n-slice constants: n = mt*16 + quad*4 + r
    floatx4 b1q[4], wr4[4];
#pragma unroll
    for (int mt = 0; mt < 4; ++mt) {
        b1q[mt] = *(const floatx4*)(b1 + mt * 16 + quad * 4);
        wr4[mt] = *(const floatx4*)(wr + mt * 16 + quad * 4);
    }

    const floatx4 z4 = (floatx4){0.f, 0.f, 0.f, 0.f};
    half8 hz;
#pragma unroll
    for (int j = 0; j < 8; ++j) hz[j] = (_Float16)0.f;

    __syncthreads();

#pragma unroll 2
    for (int li = 0; li < LC; ++li) {
        const _Float16* hlp = hl_tile + li * 128;

        // h = relu(hl16 + hr16) in packed fp16 -> B-fragments
        half8 bfr[4];
#pragma unroll
        for (int ks = 0; ks < 4; ++ks) {
            half8 hl8 = *(const half8*)(hlp + ks * 32 + quad * 8);
            bfr[ks] = __builtin_elementwise_max(hl8 + hr16[ks], hz);
        }

        // b1 folded into the FIRST MFMA's C operand (no acc-init copies;
        // same per-element accumulation order as acc=b1q + ks=0..3 chain).
        floatx4 acc[4];
#pragma unroll
        for (int mt = 0; mt < 4; ++mt)
            acc[mt] = __builtin_amdgcn_mfma_f32_16x16x32_f16(w1f[mt][0], bfr[0], b1q[mt], 0, 0, 0);
#pragma unroll
        for (int ks = 1; ks < 4; ++ks)
#pragma unroll
            for (int mt = 0; mt < 4; ++mt)
                acc[mt] = __builtin_amdgcn_mfma_f32_16x16x32_f16(w1f[mt][ks], bfr[ks], acc[mt], 0, 0, 0);

        // acc[mt][r] = h1[pair rm][n = mt*16+quad*4+r] + b1;  dot with Wr.
        // floatx4 accumulate (pk_f32-friendly, no lane-extract movs).
        floatx4 y4 = z4;
#pragma unroll
        for (int mt = 0; mt < 4; ++mt)
            y4 += __builtin_elementwise_max(acc[mt], z4) * wr4[mt];
        float y = (y4[0] + y4[1]) + (y4[2] + y4[3]);

        // quad partial; cross-quad reduction deferred to epilogue.
        part[p * PSTRIDE + quad * 17 + li] = y;
    }

    __syncthreads();

    // ---- epilogue pass 1: [li][pp] order -> outA (both) + outB (bz==0)
    {
        int li = tid >> 4;            // 0..15
        int p0 = (tid & 15) * 4;      // 0,4,..,60
        float v[4];
#pragma unroll
        for (int j = 0; j < 4; ++j) {
            const float* q = part + (p0 + j) * PSTRIDE + li;
            float yv = ((q[0] + q[17]) + (q[34] + q[51])) + brv;
            v[j] = yv > 0.f ? yv : (__expf(yv) - 1.f);   // elu
        }
        *(float4*)(outA + (lbase + li) * 1024 + rbase + p0) =
            make_float4(v[0], v[1], v[2], v[3]);
        if (bz == 0) {
            PKH4 pk;
#pragma unroll
            for (int j = 0; j < 4; ++j) pk.h[j] = (_Float16)v[j];
            *(uint2*)(outB + (lbase + li) * 1024 + rbase + p0) = pk.u;
        }
    }
    // ---- epilogue pass 2 (bz==1): [pp][li] order -> AgdT transposed
    if (bz == 1) {
        int pp = tid >> 2;            // 0..63
        int li0 = (tid & 3) * 4;      // 0,4,8,12
        PKH4 pk;
#pragma unroll
        for (int j = 0; j < 4; ++j) {
            const float* q = part + pp * PSTRIDE + li0 + j;
            float yv = ((q[0] + q[17]) + (q[34] + q[51])) + brv;
            float v = yv > 0.f ? yv : (__expf(yv) - 1.f);
            pk.h[j] = (_Float16)v;
        }
        *(uint2*)(outB + (rbase + pp) * 1024 + lbase + li0) = pk.u;
    }
}

// ---------------------------------------------------------------- final GEMM + sigmoid
// C[ch][d] = sum_g Achg[ch][g]*Agd[g][d]; fp16 MFMA, fp32 accum.
// R18: 32x32 tiles, BK=128 -> 8 K-iterations, 16 barriers. Staging is
// 2 uint4/thread per matrix (16 VGPRs live across the barrier — small enough
// to never spill; R17's 32 spilled to scratch = 85 MB of HBM write traffic).
// Register prefetch issued right after the post-write barrier; 8 ds_read_b128
// + 4 MFMAs per iteration. Even/odd global k-slice parity preserved in
// ascending order -> accumulation bitwise identical to R16/R9.
#define GSTR 136   // LDS row stride in halves (128 + 8 pad)

__global__ __launch_bounds__(256) void gemm_sig(
    const _Float16* __restrict__ Ahf,   // [1024][1024] ch x g
    const _Float16* __restrict__ BThf,  // [1024][1024] d x g
    float* __restrict__ out0)
{
    __shared__ _Float16 At[32 * GSTR];   // 8.7 KB
    __shared__ _Float16 Bt[32 * GSTR];   // 8.7 KB

    const int tid = threadIdx.x, lane = tid & 63, wave = tid >> 6;
    const int m = lane & 15, quad = lane >> 4;
    const int chbase = blockIdx.y * 32, dbase = blockIdx.x * 32;
    const int wrow = (wave >> 1) * 16, wcol = (wave & 1) * 16;

    floatx4 acc0 = (floatx4){0.f, 0.f, 0.f, 0.f};
    floatx4 acc1 = (floatx4){0.f, 0.f, 0.f, 0.f};

    // staging map: row = tid>>3 (0..31), c8 = tid&7; each thread covers
    // uint4 cols {c8, c8+8} of the 16-uint4 (128-half) row: 128B coalesced
    // segments per 8 lanes.
    const int row = tid >> 3, c8 = tid & 7;
    const _Float16* gA = Ahf + (chbase + row) * 1024 + c8 * 8;
    const _Float16* gB = BThf + (dbase + row) * 1024 + c8 * 8;

    uint4 ra0 = *(const uint4*)(gA);
    uint4 ra1 = *(const uint4*)(gA + 64);
    uint4 rb0 = *(const uint4*)(gB);
    uint4 rb1 = *(const uint4*)(gB + 64);

#pragma unroll
    for (int kb = 0; kb < 8; ++kb) {
        *(uint4*)(At + row * GSTR + c8 * 8) = ra0;
        *(uint4*)(At + row * GSTR + 64 + c8 * 8) = ra1;
        *(uint4*)(Bt + row * GSTR + c8 * 8) = rb0;
        *(uint4*)(Bt + row * GSTR + 64 + c8 * 8) = rb1;
        __syncthreads();

        // prefetch next K-block (latency hides under the MFMA phase)
        if (kb < 7) {
            ra0 = *(const uint4*)(gA + (kb + 1) * 128);
            ra1 = *(const uint4*)(gA + (kb + 1) * 128 + 64);
            rb0 = *(const uint4*)(gB + (kb + 1) * 128);
            rb1 = *(const uint4*)(gB + (kb + 1) * 128 + 64);
        }

        // 4 k-slices of K=32; global slice s = kb*4+ks. Even s -> acc0,
        // odd s -> acc1, ascending -> bitwise identical to the BK=64 loop.
#pragma unroll
        for (int ks = 0; ks < 4; ks += 2) {
            half8 a0 = *(const half8*)(At + (wrow + m) * GSTR + ks * 32 + quad * 8);
            half8 b0 = *(const half8*)(Bt + (wcol + m) * GSTR + ks * 32 + quad * 8);
            half8 a1 = *(const half8*)(At + (wrow + m) * GSTR + (ks + 1) * 32 + quad * 8);
            half8 b1 = *(const half8*)(Bt + (wcol + m) * GSTR + (ks + 1) * 32 + quad * 8);
            acc0 = __builtin_amdgcn_mfma_f32_16x16x32_f16(a0, b0, acc0, 0, 0, 0);
            acc1 = __builtin_amdgcn_mfma_f32_16x16x32_f16(a1, b1, acc1, 0, 0, 0);
        }
        __syncthreads();
    }

    floatx4 acc = acc0 + acc1;
#pragma unroll
    for (int r = 0; r < 4; ++r) {
        int row_o = chbase + wrow + quad * 4 + r;
        int col_o = dbase + wcol + m;
        // sigmoid via fast exp + hw rcp (~1e-7 abs drift, well under tolerance)
        float e = __expf(-acc[r]);
        out0[row_o * 1024 + col_o] = __builtin_amdgcn_rcpf(1.f + e);
    }
}

// ---------------------------------------------------------------- launch
extern "C" void kernel_launch(void* const* d_in, const int* in_sizes, int n_in,
                              void* d_out, int out_size, void* d_ws, size_t ws_size,
                              hipStream_t stream) {
    const float* Xch = (const float*)d_in[0];
    const float* Xg  = (const float*)d_in[1];
    const float* Xd  = (const float*)d_in[2];
    const float* Wc0 = (const float*)d_in[3];
    const float* bc0 = (const float*)d_in[4];
    const float* Wc1 = (const float*)d_in[5];
    const float* bc1 = (const float*)d_in[6];
    const float* Wcr = (const float*)d_in[7];
    const float* bcr = (const float*)d_in[8];
    const float* Wd0 = (const float*)d_in[9];
    const float* bd0 = (const float*)d_in[10];
    const float* Wd1 = (const float*)d_in[11];
    const float* bd1 = (const float*)d_in[12];
    const float* Wdr = (const float*)d_in[13];
    const float* bdr = (const float*)d_in[14];

    float* out = (float*)d_out;
    _Float16* hlhr = (_Float16*)d_ws;            // 4x1024x128 fp16 = 1 MB
    _Float16* wsh = hlhr + 524288;               // Achg f16 1M + AgdT f16 1M
    _Float16* w1frag = wsh + 2097152;            // 16384 f16

    prep<<<2112, 256, 0, stream>>>(Xch, Xg, Xd, Wc0, bc0, Wd0, bd0, Wc1, Wd1,
                                   hlhr, w1frag);

    dim3 gb(16, 64, 2);   // (r-chunks of 64, l-chunks of 16, branch)
    branch_kernel<<<gb, 256, 0, stream>>>(hlhr, bc1, Wcr, bcr, bd1, Wdr, bdr,
                                          w1frag, out, wsh);

    dim3 gg(32, 32);
    gemm_sig<<<gg, 256, 0, stream>>>(wsh, wsh + 1048576, out);
}